// Round 1
// baseline (708.513 us; speedup 1.0000x reference)
//
#include <hip/hip_runtime.h>
#include <cstdint>
#include <cstddef>

#define N_NODES 50000
#define E_EDGES 800000
#define IN_F    128
#define PCOLS   512   // P layout: [0,96) Y0 | [96,192) Zpre | [192,288) Zblk | [288,480) Zpost | [480,512) pad

// ---------- pack weights into Wcat [128,512] + bcat[512] ----------
__global__ void pack_weights(const float* __restrict__ Wp,  const float* __restrict__ bp,
                             const float* __restrict__ Tp,  const float* __restrict__ bTp,
                             const float* __restrict__ Tb,  const float* __restrict__ bTb,
                             const float* __restrict__ Tpo, const float* __restrict__ bTpo,
                             float* __restrict__ Wcat, float* __restrict__ bcat)
{
    int id = blockIdx.x * 256 + threadIdx.x;
    if (id >= IN_F * PCOLS) return;
    int k = id >> 9;
    int c = id & 511;
    float v;
    if      (c < 96)  v = Wp [k*96  + c];
    else if (c < 192) v = Tp [k*96  + (c-96)];
    else if (c < 288) v = Tb [k*96  + (c-192)];
    else if (c < 480) v = Tpo[k*192 + (c-288)];
    else              v = 0.f;
    Wcat[id] = v;
    if (k == 0) {
        float b;
        if      (c < 96)  b = bp  [c];
        else if (c < 192) b = bTp [c-96];
        else if (c < 288) b = bTb [c-192];
        else if (c < 480) b = bTpo[c-288];
        else              b = 0.f;
        bcat[c] = b;
    }
}

// ---------- row_ptr via binary search on sorted tgt ----------
__global__ void build_row_ptr(const int* __restrict__ tgt, int* __restrict__ row_ptr,
                              int E, int Np1)
{
    int t = blockIdx.x * 256 + threadIdx.x;
    if (t >= Np1) return;
    int lo = 0, hi = E;
    while (lo < hi) {
        int mid = (lo + hi) >> 1;
        if (tgt[mid] < t) lo = mid + 1; else hi = mid;
    }
    row_ptr[t] = lo;
}

// ---------- fused GEMM: P[M,512] = data[M,128] @ Wcat[128,512] + bcat ----------
#define ROW_FMA(i, av)                                            \
    acc[i][0] += av.x*b0.x + av.y*b1.x + av.z*b2.x + av.w*b3.x;   \
    acc[i][1] += av.x*b0.y + av.y*b1.y + av.z*b2.y + av.w*b3.y;   \
    acc[i][2] += av.x*b0.z + av.y*b1.z + av.z*b2.z + av.w*b3.z;   \
    acc[i][3] += av.x*b0.w + av.y*b1.w + av.z*b2.w + av.w*b3.w;

__global__ __launch_bounds__(256) void gemm_fused(const float* __restrict__ A,
                                                  const float* __restrict__ Wcat,
                                                  const float* __restrict__ bcat,
                                                  float* __restrict__ P, int M)
{
    __shared__ float As[64][68];   // stride 68 floats = 272B (16B-aligned rows)
    __shared__ float Bs[64][68];
    int tid = threadIdx.x;
    int mb = blockIdx.x * 64;
    int nb = blockIdx.y * 64;
    int tx = tid & 15, ty = tid >> 4;
    float acc[4][4] = {};

    for (int kt = 0; kt < 128; kt += 64) {
        #pragma unroll
        for (int r = 0; r < 4; ++r) {
            int id = tid + 256*r;
            int m  = id >> 4;
            int k4 = (id & 15) << 2;
            int gm = mb + m;
            float4 v = make_float4(0.f,0.f,0.f,0.f);
            if (gm < M) v = *(const float4*)(A + (size_t)gm*IN_F + kt + k4);
            *(float4*)(&As[m][k4]) = v;
        }
        #pragma unroll
        for (int r = 0; r < 4; ++r) {
            int id = tid + 256*r;
            int kk = id >> 4;
            int n4 = (id & 15) << 2;
            float4 v = *(const float4*)(Wcat + (size_t)(kt+kk)*PCOLS + nb + n4);
            *(float4*)(&Bs[kk][n4]) = v;
        }
        __syncthreads();
        #pragma unroll
        for (int k = 0; k < 64; k += 4) {
            float4 a0 = *(const float4*)(&As[ty*4+0][k]);
            float4 a1 = *(const float4*)(&As[ty*4+1][k]);
            float4 a2 = *(const float4*)(&As[ty*4+2][k]);
            float4 a3 = *(const float4*)(&As[ty*4+3][k]);
            float4 b0 = *(const float4*)(&Bs[k+0][tx*4]);
            float4 b1 = *(const float4*)(&Bs[k+1][tx*4]);
            float4 b2 = *(const float4*)(&Bs[k+2][tx*4]);
            float4 b3 = *(const float4*)(&Bs[k+3][tx*4]);
            ROW_FMA(0, a0); ROW_FMA(1, a1); ROW_FMA(2, a2); ROW_FMA(3, a3);
        }
        __syncthreads();
    }
    float4 bias = *(const float4*)(bcat + nb + tx*4);
    #pragma unroll
    for (int i = 0; i < 4; ++i) {
        int gm = mb + ty*4 + i;
        if (gm < M) {
            float4 o;
            o.x = acc[i][0] + bias.x; o.y = acc[i][1] + bias.y;
            o.z = acc[i][2] + bias.z; o.w = acc[i][3] + bias.w;
            *(float4*)(P + (size_t)gm*PCOLS + nb + tx*4) = o;
        }
    }
}

// ---------- Laplacian(X)[t] + Z[t], relu -> out[t]  (96 features, wave per node) ----------
__global__ void lap_relu96(const float* __restrict__ X, int xstride,
                           const float* __restrict__ Z,   // row stride PCOLS
                           const int* __restrict__ src, const int* __restrict__ row_ptr,
                           float* __restrict__ out, int N)
{
    int wid  = (int)(((size_t)blockIdx.x * blockDim.x + threadIdx.x) >> 6);
    int lane = threadIdx.x & 63;
    if (wid >= N) return;
    int lo = row_ptr[wid], hi = row_ptr[wid+1];
    const float* xr = X + (size_t)wid * xstride;
    bool lo32 = lane < 32;
    float a0 = 0.f, a1 = 0.f;
    for (int e = lo; e < hi; ++e) {
        int s = src[e];
        const float* sr = X + (size_t)s * xstride;
        a0 += sr[lane];
        if (lo32) a1 += sr[64 + lane];
    }
    int deg = hi - lo;
    float inv = deg > 0 ? 1.f / (float)deg : 0.f;
    float mf  = deg > 0 ? 1.f : 0.f;
    const float* zr = Z + (size_t)wid * PCOLS;
    float o0 = fmaxf(mf * xr[lane] - a0 * inv + zr[lane], 0.f);
    out[(size_t)wid*96 + lane] = o0;
    if (lo32) {
        float o1 = fmaxf(mf * xr[64+lane] - a1 * inv + zr[64+lane], 0.f);
        out[(size_t)wid*96 + 64 + lane] = o1;
    }
}

// ---------- grouped 1x1 conv: out[t][w*HO+j] = b[w][j] + sum_i X[t][w*32+i]*Wg[w][i][j] ----------
template<int HO>
__global__ void grouped_conv(const float* __restrict__ X,   // [N,96]
                             const float* __restrict__ Wg,  // [3,32,HO] flat
                             const float* __restrict__ bg,  // [3,HO]
                             float* __restrict__ out, int N)
{
    __shared__ float wS[3*32*HO];
    __shared__ float bS[3*HO];
    for (int i = threadIdx.x; i < 3*32*HO; i += 256) wS[i] = Wg[i];
    for (int i = threadIdx.x; i < 3*HO;    i += 256) bS[i] = bg[i];
    __syncthreads();
    int gid = blockIdx.x * 256 + threadIdx.x;
    int t = gid / (3*HO);
    int c = gid % (3*HO);
    if (t >= N) return;
    int w = c / HO, j = c - w*HO;
    const float* xr = X + (size_t)t*96 + w*32;
    const float* wp = &wS[(w*32)*HO + j];
    float s = bS[c];
    #pragma unroll
    for (int i = 0; i < 32; ++i) s += xr[i] * wp[i*HO];
    out[(size_t)t*(3*HO) + c] = s;
}

// ---------- final: relu(Lap(h2)+Zpost) then mean over width-triples -> out[N,64] ----------
__global__ void lap_final(const float* __restrict__ X,   // [N,192]
                          const float* __restrict__ Z,   // row stride PCOLS (offset 288 applied)
                          const int* __restrict__ src, const int* __restrict__ row_ptr,
                          float* __restrict__ out, int N)
{
    __shared__ float sm[4][192];
    int wavein = threadIdx.x >> 6;
    int wid  = (int)(((size_t)blockIdx.x * blockDim.x + threadIdx.x) >> 6);
    int lane = threadIdx.x & 63;
    if (wid >= N) return;   // never triggers (grid exact), no barrier below this that others wait on
    int lo = row_ptr[wid], hi = row_ptr[wid+1];
    const float* xr = X + (size_t)wid * 192;
    float a0 = 0.f, a1 = 0.f, a2 = 0.f;
    for (int e = lo; e < hi; ++e) {
        const float* sr = X + (size_t)src[e] * 192;
        a0 += sr[lane];
        a1 += sr[64 + lane];
        a2 += sr[128 + lane];
    }
    int deg = hi - lo;
    float inv = deg > 0 ? 1.f / (float)deg : 0.f;
    float mf  = deg > 0 ? 1.f : 0.f;
    const float* zr = Z + (size_t)wid * PCOLS;
    float o0 = fmaxf(mf * xr[lane]      - a0 * inv + zr[lane],      0.f);
    float o1 = fmaxf(mf * xr[64+lane]   - a1 * inv + zr[64+lane],   0.f);
    float o2 = fmaxf(mf * xr[128+lane]  - a2 * inv + zr[128+lane],  0.f);
    sm[wavein][lane]       = o0;
    sm[wavein][64 + lane]  = o1;
    sm[wavein][128 + lane] = o2;
    __syncthreads();   // all 4 waves always alive (grid exact: 50000 waves = N)
    float r = (sm[wavein][3*lane] + sm[wavein][3*lane+1] + sm[wavein][3*lane+2]) * (1.0f/3.0f);
    out[(size_t)wid*64 + lane] = r;
}

extern "C" void kernel_launch(void* const* d_in, const int* in_sizes, int n_in,
                              void* d_out, int out_size, void* d_ws, size_t ws_size,
                              hipStream_t stream)
{
    const float* data    = (const float*)d_in[0];
    const int*   src     = (const int*)  d_in[1];
    const int*   tgt     = (const int*)  d_in[2];
    const float* W_pre   = (const float*)d_in[3];
    const float* b_pre   = (const float*)d_in[4];
    const float* T_pre   = (const float*)d_in[5];
    const float* bT_pre  = (const float*)d_in[6];
    const float* W_blk   = (const float*)d_in[7];
    const float* b_blk   = (const float*)d_in[8];
    const float* T_blk   = (const float*)d_in[9];
    const float* bT_blk  = (const float*)d_in[10];
    const float* W_post  = (const float*)d_in[11];
    const float* b_post  = (const float*)d_in[12];
    const float* T_post  = (const float*)d_in[13];
    const float* bT_post = (const float*)d_in[14];
    float* out = (float*)d_out;

    float* ws   = (float*)d_ws;
    float* P    = ws;                                   // N*512
    float* buf1 = P    + (size_t)N_NODES * PCOLS;       // N*96 (out1, then out2)
    float* h1   = buf1 + (size_t)N_NODES * 96;          // N*96
    float* h2   = h1   + (size_t)N_NODES * 96;          // N*192
    float* Wcat = h2   + (size_t)N_NODES * 192;         // 128*512
    float* bcat = Wcat + 128*512;                       // 512
    int*   row_ptr = (int*)(bcat + 512);                // N+1

    pack_weights<<<(IN_F*PCOLS + 255)/256, 256, 0, stream>>>(
        W_pre, b_pre, T_pre, bT_pre, T_blk, bT_blk, T_post, bT_post, Wcat, bcat);

    build_row_ptr<<<(N_NODES + 1 + 255)/256, 256, 0, stream>>>(tgt, row_ptr, E_EDGES, N_NODES + 1);

    dim3 gg((N_NODES + 63)/64, PCOLS/64);
    gemm_fused<<<gg, 256, 0, stream>>>(data, Wcat, bcat, P, N_NODES);

    // layer 1: out1 = relu(Lap(Y0) + Zpre)
    lap_relu96<<<(N_NODES*64)/256, 256, 0, stream>>>(P, PCOLS, P + 96, src, row_ptr, buf1, N_NODES);
    // h1 = grouped_conv_blk(out1)
    grouped_conv<32><<<(N_NODES*96)/256, 256, 0, stream>>>(buf1, W_blk, b_blk, h1, N_NODES);
    // layer 2: out2 = relu(Lap(h1) + Zblk)
    lap_relu96<<<(N_NODES*64)/256, 256, 0, stream>>>(h1, 96, P + 192, src, row_ptr, buf1, N_NODES);
    // h2 = grouped_conv_post(out2)
    grouped_conv<64><<<(N_NODES*192)/256, 256, 0, stream>>>(buf1, W_post, b_post, h2, N_NODES);
    // layer 3 + width-mean epilogue
    lap_final<<<(N_NODES*64)/256, 256, 0, stream>>>(h2, P + 288, src, row_ptr, out, N_NODES);
}

// Round 2
// 516.231 us; speedup vs baseline: 1.3725x; 1.3725x over previous
//
#include <hip/hip_runtime.h>
#include <cstdint>
#include <cstddef>

#define N_NODES 50000
#define E_EDGES 800000
#define IN_F    128
#define PCOLS   512   // P layout: [0,96) Y0 | [96,192) Zpre | [192,288) Zblk | [288,480) Zpost | [480,512) pad

// ---------- pack weights into Wcat [128,512] + bcat[512] ----------
__global__ void pack_weights(const float* __restrict__ Wp,  const float* __restrict__ bp,
                             const float* __restrict__ Tp,  const float* __restrict__ bTp,
                             const float* __restrict__ Tb,  const float* __restrict__ bTb,
                             const float* __restrict__ Tpo, const float* __restrict__ bTpo,
                             float* __restrict__ Wcat, float* __restrict__ bcat)
{
    int id = blockIdx.x * 256 + threadIdx.x;
    if (id >= IN_F * PCOLS) return;
    int k = id >> 9;
    int c = id & 511;
    float v;
    if      (c < 96)  v = Wp [k*96  + c];
    else if (c < 192) v = Tp [k*96  + (c-96)];
    else if (c < 288) v = Tb [k*96  + (c-192)];
    else if (c < 480) v = Tpo[k*192 + (c-288)];
    else              v = 0.f;
    Wcat[id] = v;
    if (k == 0) {
        float b;
        if      (c < 96)  b = bp  [c];
        else if (c < 192) b = bTp [c-96];
        else if (c < 288) b = bTb [c-192];
        else if (c < 480) b = bTpo[c-288];
        else              b = 0.f;
        bcat[c] = b;
    }
}

// ---------- row_ptr via binary search on sorted tgt ----------
__global__ void build_row_ptr(const int* __restrict__ tgt, int* __restrict__ row_ptr,
                              int E, int Np1)
{
    int t = blockIdx.x * 256 + threadIdx.x;
    if (t >= Np1) return;
    int lo = 0, hi = E;
    while (lo < hi) {
        int mid = (lo + hi) >> 1;
        if (tgt[mid] < t) lo = mid + 1; else hi = mid;
    }
    row_ptr[t] = lo;
}

// ---------- fused GEMM: P[M,512] = data[M,128] @ Wcat[128,512] + bcat ----------
// 128x128 tile per 256-thread block, 8x8 microtile, BK=32, A transposed in LDS.
#define BM 128
#define BN 128
#define BK 32
#define BMP (BM + 4)

__global__ __launch_bounds__(256, 4) void gemm_fused(const float* __restrict__ A,
                                                     const float* __restrict__ Wcat,
                                                     const float* __restrict__ bcat,
                                                     float* __restrict__ P, int M)
{
    __shared__ float As[BK][BMP];   // transposed: As[k][m]
    __shared__ float Bs[BK][BN];
    int tid = threadIdx.x;
    int mb = blockIdx.x * BM;
    int nb = blockIdx.y * BN;
    int tx = tid & 15;    // 16 col-groups of 8 cols
    int ty = tid >> 4;    // 16 row-groups of 8 rows
    float acc[8][8] = {};

    for (int kt = 0; kt < IN_F; kt += BK) {
        // load A tile 128x32 (as float4 along k), store transposed
        #pragma unroll
        for (int r = 0; r < 4; ++r) {
            int idx = tid + 256*r;
            int m   = idx >> 3;          // 0..127
            int k4  = (idx & 7) << 2;    // 0,4,...,28
            int gm  = mb + m;
            float4 v = make_float4(0.f,0.f,0.f,0.f);
            if (gm < M) v = *(const float4*)(A + (size_t)gm*IN_F + kt + k4);
            As[k4+0][m] = v.x; As[k4+1][m] = v.y; As[k4+2][m] = v.z; As[k4+3][m] = v.w;
        }
        // load B tile 32x128
        #pragma unroll
        for (int r = 0; r < 4; ++r) {
            int idx = tid + 256*r;
            int k   = idx >> 5;          // 0..31
            int n4  = (idx & 31) << 2;   // 0..124
            float4 v = *(const float4*)(Wcat + (size_t)(kt+k)*PCOLS + nb + n4);
            *(float4*)(&Bs[k][n4]) = v;
        }
        __syncthreads();
        #pragma unroll
        for (int k = 0; k < BK; ++k) {
            float4 a0 = *(const float4*)(&As[k][ty*8]);
            float4 a1 = *(const float4*)(&As[k][ty*8+4]);
            float4 b0 = *(const float4*)(&Bs[k][tx*8]);
            float4 b1 = *(const float4*)(&Bs[k][tx*8+4]);
            float av[8] = {a0.x,a0.y,a0.z,a0.w,a1.x,a1.y,a1.z,a1.w};
            float bv[8] = {b0.x,b0.y,b0.z,b0.w,b1.x,b1.y,b1.z,b1.w};
            #pragma unroll
            for (int i = 0; i < 8; ++i)
                #pragma unroll
                for (int jj = 0; jj < 8; ++jj)
                    acc[i][jj] += av[i] * bv[jj];
        }
        __syncthreads();
    }
    float4 bias0 = *(const float4*)(bcat + nb + tx*8);
    float4 bias1 = *(const float4*)(bcat + nb + tx*8 + 4);
    #pragma unroll
    for (int i = 0; i < 8; ++i) {
        int gm = mb + ty*8 + i;
        if (gm < M) {
            float4 o0, o1;
            o0.x = acc[i][0]+bias0.x; o0.y = acc[i][1]+bias0.y;
            o0.z = acc[i][2]+bias0.z; o0.w = acc[i][3]+bias0.w;
            o1.x = acc[i][4]+bias1.x; o1.y = acc[i][5]+bias1.y;
            o1.z = acc[i][6]+bias1.z; o1.w = acc[i][7]+bias1.w;
            *(float4*)(P + (size_t)gm*PCOLS + nb + tx*8)     = o0;
            *(float4*)(P + (size_t)gm*PCOLS + nb + tx*8 + 4) = o1;
        }
    }
}

// ---------- Laplacian(X)[t] + Z[t], relu -> out[t]  (96 features, wave per node) ----------
// Cooperative src load + shuffle broadcast + unroll-4 for load ILP.
__global__ void lap_relu96(const float* __restrict__ X, int xstride,
                           const float* __restrict__ Z,   // row stride PCOLS
                           const int* __restrict__ src, const int* __restrict__ row_ptr,
                           float* __restrict__ out, int N)
{
    int wid  = (int)(((size_t)blockIdx.x * blockDim.x + threadIdx.x) >> 6);
    int lane = threadIdx.x & 63;
    if (wid >= N) return;
    int lo = row_ptr[wid], hi = row_ptr[wid+1];
    bool lo32 = lane < 32;
    int off2 = lo32 ? 64 + lane : lane;   // inactive lanes re-read same line (no extra traffic)
    float a0=0.f,a1=0.f,a2=0.f,a3=0.f;
    float b0=0.f,b1=0.f,b2=0.f,b3=0.f;
    for (int base = lo; base < hi; base += 64) {
        int cnt = hi - base; if (cnt > 64) cnt = 64;
        int sv = src[base + (lane < cnt ? lane : cnt-1)];
        int j = 0;
        for (; j + 4 <= cnt; j += 4) {
            int i0 = __shfl(sv, j),   i1 = __shfl(sv, j+1);
            int i2 = __shfl(sv, j+2), i3 = __shfl(sv, j+3);
            const float* r0 = X + (size_t)i0 * xstride;
            const float* r1 = X + (size_t)i1 * xstride;
            const float* r2 = X + (size_t)i2 * xstride;
            const float* r3 = X + (size_t)i3 * xstride;
            float x0 = r0[lane], x1 = r1[lane], x2 = r2[lane], x3 = r3[lane];
            float y0 = r0[off2], y1 = r1[off2], y2 = r2[off2], y3 = r3[off2];
            a0 += x0; a1 += x1; a2 += x2; a3 += x3;
            b0 += y0; b1 += y1; b2 += y2; b3 += y3;
        }
        for (; j < cnt; ++j) {
            int i0 = __shfl(sv, j);
            const float* r0 = X + (size_t)i0 * xstride;
            a0 += r0[lane];
            b0 += r0[off2];
        }
    }
    float s0 = (a0+a1)+(a2+a3);
    float s1 = (b0+b1)+(b2+b3);
    int deg = hi - lo;
    float inv = deg > 0 ? 1.f / (float)deg : 0.f;
    float mf  = deg > 0 ? 1.f : 0.f;
    const float* xr = X + (size_t)wid * xstride;
    const float* zr = Z + (size_t)wid * PCOLS;
    float o0 = fmaxf(mf * xr[lane] - s0 * inv + zr[lane], 0.f);
    out[(size_t)wid*96 + lane] = o0;
    if (lo32) {
        float o1 = fmaxf(mf * xr[64+lane] - s1 * inv + zr[64+lane], 0.f);
        out[(size_t)wid*96 + 64 + lane] = o1;
    }
}

// ---------- grouped 1x1 conv: out[t][w*HO+j] = b[w][j] + sum_i X[t][w*32+i]*Wg[w][i][j] ----------
template<int HO>
__global__ void grouped_conv(const float* __restrict__ X,   // [N,96]
                             const float* __restrict__ Wg,  // [3,32,HO] flat
                             const float* __restrict__ bg,  // [3,HO]
                             float* __restrict__ out, int N)
{
    __shared__ float wS[3*32*HO];
    __shared__ float bS[3*HO];
    for (int i = threadIdx.x; i < 3*32*HO; i += 256) wS[i] = Wg[i];
    for (int i = threadIdx.x; i < 3*HO;    i += 256) bS[i] = bg[i];
    __syncthreads();
    int gid = blockIdx.x * 256 + threadIdx.x;
    int t = gid / (3*HO);
    int c = gid % (3*HO);
    if (t >= N) return;
    int w = c / HO, j = c - w*HO;
    const float* xr = X + (size_t)t*96 + w*32;
    const float* wp = &wS[(w*32)*HO + j];
    float s = bS[c];
    #pragma unroll
    for (int i = 0; i < 32; ++i) s += xr[i] * wp[i*HO];
    out[(size_t)t*(3*HO) + c] = s;
}

// ---------- final: relu(Lap(h2)+Zpost) then mean over width-triples -> out[N,64] ----------
__global__ void lap_final(const float* __restrict__ X,   // [N,192]
                          const float* __restrict__ Z,   // row stride PCOLS (offset 288 applied)
                          const int* __restrict__ src, const int* __restrict__ row_ptr,
                          float* __restrict__ out, int N)
{
    __shared__ float sm[4][192];
    int wavein = threadIdx.x >> 6;
    int wid  = (int)(((size_t)blockIdx.x * blockDim.x + threadIdx.x) >> 6);
    int lane = threadIdx.x & 63;
    if (wid >= N) return;   // never triggers (grid exact)
    int lo = row_ptr[wid], hi = row_ptr[wid+1];
    float a0=0.f,a1=0.f,a2=0.f,a3=0.f;
    float b0=0.f,b1=0.f,b2=0.f,b3=0.f;
    float c0=0.f,c1=0.f,c2=0.f,c3=0.f;
    for (int base = lo; base < hi; base += 64) {
        int cnt = hi - base; if (cnt > 64) cnt = 64;
        int sv = src[base + (lane < cnt ? lane : cnt-1)];
        int j = 0;
        for (; j + 4 <= cnt; j += 4) {
            int i0 = __shfl(sv, j),   i1 = __shfl(sv, j+1);
            int i2 = __shfl(sv, j+2), i3 = __shfl(sv, j+3);
            const float* r0 = X + (size_t)i0 * 192;
            const float* r1 = X + (size_t)i1 * 192;
            const float* r2 = X + (size_t)i2 * 192;
            const float* r3 = X + (size_t)i3 * 192;
            float x0=r0[lane],     x1=r1[lane],     x2=r2[lane],     x3=r3[lane];
            float y0=r0[64+lane],  y1=r1[64+lane],  y2=r2[64+lane],  y3=r3[64+lane];
            float z0=r0[128+lane], z1=r1[128+lane], z2=r2[128+lane], z3=r3[128+lane];
            a0+=x0; a1+=x1; a2+=x2; a3+=x3;
            b0+=y0; b1+=y1; b2+=y2; b3+=y3;
            c0+=z0; c1+=z1; c2+=z2; c3+=z3;
        }
        for (; j < cnt; ++j) {
            int i0 = __shfl(sv, j);
            const float* r0 = X + (size_t)i0 * 192;
            a0 += r0[lane]; b0 += r0[64+lane]; c0 += r0[128+lane];
        }
    }
    float s0 = (a0+a1)+(a2+a3);
    float s1 = (b0+b1)+(b2+b3);
    float s2 = (c0+c1)+(c2+c3);
    int deg = hi - lo;
    float inv = deg > 0 ? 1.f / (float)deg : 0.f;
    float mf  = deg > 0 ? 1.f : 0.f;
    const float* xr = X + (size_t)wid * 192;
    const float* zr = Z + (size_t)wid * PCOLS;
    float o0 = fmaxf(mf * xr[lane]      - s0 * inv + zr[lane],      0.f);
    float o1 = fmaxf(mf * xr[64+lane]   - s1 * inv + zr[64+lane],   0.f);
    float o2 = fmaxf(mf * xr[128+lane]  - s2 * inv + zr[128+lane],  0.f);
    sm[wavein][lane]       = o0;
    sm[wavein][64 + lane]  = o1;
    sm[wavein][128 + lane] = o2;
    __syncthreads();   // all 4 waves always alive (grid exact: 50000 waves = N)
    float r = (sm[wavein][3*lane] + sm[wavein][3*lane+1] + sm[wavein][3*lane+2]) * (1.0f/3.0f);
    out[(size_t)wid*64 + lane] = r;
}

extern "C" void kernel_launch(void* const* d_in, const int* in_sizes, int n_in,
                              void* d_out, int out_size, void* d_ws, size_t ws_size,
                              hipStream_t stream)
{
    const float* data    = (const float*)d_in[0];
    const int*   src     = (const int*)  d_in[1];
    const int*   tgt     = (const int*)  d_in[2];
    const float* W_pre   = (const float*)d_in[3];
    const float* b_pre   = (const float*)d_in[4];
    const float* T_pre   = (const float*)d_in[5];
    const float* bT_pre  = (const float*)d_in[6];
    const float* W_blk   = (const float*)d_in[7];
    const float* b_blk   = (const float*)d_in[8];
    const float* T_blk   = (const float*)d_in[9];
    const float* bT_blk  = (const float*)d_in[10];
    const float* W_post  = (const float*)d_in[11];
    const float* b_post  = (const float*)d_in[12];
    const float* T_post  = (const float*)d_in[13];
    const float* bT_post = (const float*)d_in[14];
    float* out = (float*)d_out;

    float* ws   = (float*)d_ws;
    float* P    = ws;                                   // N*512
    float* buf1 = P    + (size_t)N_NODES * PCOLS;       // N*96 (out1, then out2)
    float* h1   = buf1 + (size_t)N_NODES * 96;          // N*96
    float* h2   = h1   + (size_t)N_NODES * 96;          // N*192
    float* Wcat = h2   + (size_t)N_NODES * 192;         // 128*512
    float* bcat = Wcat + 128*512;                       // 512
    int*   row_ptr = (int*)(bcat + 512);                // N+1

    pack_weights<<<(IN_F*PCOLS + 255)/256, 256, 0, stream>>>(
        W_pre, b_pre, T_pre, bT_pre, T_blk, bT_blk, T_post, bT_post, Wcat, bcat);

    build_row_ptr<<<(N_NODES + 1 + 255)/256, 256, 0, stream>>>(tgt, row_ptr, E_EDGES, N_NODES + 1);

    dim3 gg((N_NODES + BM - 1)/BM, PCOLS/BN);
    gemm_fused<<<gg, 256, 0, stream>>>(data, Wcat, bcat, P, N_NODES);

    // layer 1: out1 = relu(Lap(Y0) + Zpre)
    lap_relu96<<<(N_NODES*64)/256, 256, 0, stream>>>(P, PCOLS, P + 96, src, row_ptr, buf1, N_NODES);
    // h1 = grouped_conv_blk(out1)
    grouped_conv<32><<<(N_NODES*96)/256, 256, 0, stream>>>(buf1, W_blk, b_blk, h1, N_NODES);
    // layer 2: out2 = relu(Lap(h1) + Zblk)
    lap_relu96<<<(N_NODES*64)/256, 256, 0, stream>>>(h1, 96, P + 192, src, row_ptr, buf1, N_NODES);
    // h2 = grouped_conv_post(out2)
    grouped_conv<64><<<(N_NODES*192)/256, 256, 0, stream>>>(buf1, W_post, b_post, h2, N_NODES);
    // layer 3 + width-mean epilogue
    lap_final<<<(N_NODES*64)/256, 256, 0, stream>>>(h2, P + 288, src, row_ptr, out, N_NODES);
}

// Round 3
// 383.157 us; speedup vs baseline: 1.8491x; 1.3473x over previous
//
#include <hip/hip_runtime.h>
#include <cstdint>
#include <cstddef>

#define N_NODES 50000
#define E_EDGES 800000
#define IN_F    128
#define PCOLS   512   // P: [0,96) Y0 | [96,192) Zpre | [192,288) Zblk | [288,480) Zpost | pad

typedef unsigned short ushortT;
typedef unsigned int   uintT;

__device__ __forceinline__ float bflo(uintT u){ union{uintT i;float f;}c; c.i=u<<16; return c.f; }
__device__ __forceinline__ float bfhi(uintT u){ union{uintT i;float f;}c; c.i=u&0xFFFF0000u; return c.f; }
__device__ __forceinline__ ushortT f2bfu(float f){
    union{float f;uintT u;}c; c.f=f;
    uintT r = c.u + 0x7FFF + ((c.u>>16)&1);
    return (ushortT)(r>>16);
}

// ---------- pack weights into Wcat [128,512] + bcat[512] ----------
__global__ void pack_weights(const float* __restrict__ Wp,  const float* __restrict__ bp,
                             const float* __restrict__ Tp,  const float* __restrict__ bTp,
                             const float* __restrict__ Tb,  const float* __restrict__ bTb,
                             const float* __restrict__ Tpo, const float* __restrict__ bTpo,
                             float* __restrict__ Wcat, float* __restrict__ bcat)
{
    int id = blockIdx.x * 256 + threadIdx.x;
    if (id >= IN_F * PCOLS) return;
    int k = id >> 9;
    int c = id & 511;
    float v;
    if      (c < 96)  v = Wp [k*96  + c];
    else if (c < 192) v = Tp [k*96  + (c-96)];
    else if (c < 288) v = Tb [k*96  + (c-192)];
    else if (c < 480) v = Tpo[k*192 + (c-288)];
    else              v = 0.f;
    Wcat[id] = v;
    if (k == 0) {
        float b;
        if      (c < 96)  b = bp  [c];
        else if (c < 192) b = bTp [c-96];
        else if (c < 288) b = bTb [c-192];
        else if (c < 480) b = bTpo[c-288];
        else              b = 0.f;
        bcat[c] = b;
    }
}

// ---------- row_ptr via binary search on sorted tgt ----------
__global__ void build_row_ptr(const int* __restrict__ tgt, int* __restrict__ row_ptr,
                              int E, int Np1)
{
    int t = blockIdx.x * 256 + threadIdx.x;
    if (t >= Np1) return;
    int lo = 0, hi = E;
    while (lo < hi) {
        int mid = (lo + hi) >> 1;
        if (tgt[mid] < t) lo = mid + 1; else hi = mid;
    }
    row_ptr[t] = lo;
}

// ---------- fused GEMM: P[M,512] = data[M,128] @ Wcat[128,512] + bcat ----------
#define BM 128
#define BN 128
#define BK 32
#define BMP (BM + 4)

__device__ __forceinline__ void fma4(float4& a, float s, const float4& b) {
    a.x = fmaf(s, b.x, a.x); a.y = fmaf(s, b.y, a.y);
    a.z = fmaf(s, b.z, a.z); a.w = fmaf(s, b.w, a.w);
}

__global__ __launch_bounds__(256, 2) void gemm_fused(const float* __restrict__ A,
                                                     const float* __restrict__ Wcat,
                                                     const float* __restrict__ bcat,
                                                     float* __restrict__ P,
                                                     ushortT* __restrict__ Y0b, int M)
{
    __shared__ float As[BK][BMP];   // transposed: As[k][m]
    __shared__ float Bs[BK][BN];
    int tid = threadIdx.x;
    int nb = blockIdx.x * BN;   // col tile (x fastest -> col tiles of same rows co-dispatch)
    int mb = blockIdx.y * BM;
    int tx = tid & 15;          // col group: cols {tx*4..+3} and {64+tx*4..+3}
    int ty = tid >> 4;          // row group: rows ty*8..ty*8+7
    float4 c0[8], c1[8];
    #pragma unroll
    for (int i = 0; i < 8; ++i) { c0[i] = make_float4(0,0,0,0); c1[i] = make_float4(0,0,0,0); }

    for (int kt = 0; kt < IN_F; kt += BK) {
        #pragma unroll
        for (int r = 0; r < 4; ++r) {
            int idx = tid + 256*r;
            int m   = idx >> 3;
            int k4  = (idx & 7) << 2;
            int gm  = mb + m;
            float4 v = make_float4(0.f,0.f,0.f,0.f);
            if (gm < M) v = *(const float4*)(A + (size_t)gm*IN_F + kt + k4);
            As[k4+0][m] = v.x; As[k4+1][m] = v.y; As[k4+2][m] = v.z; As[k4+3][m] = v.w;
        }
        #pragma unroll
        for (int r = 0; r < 4; ++r) {
            int idx = tid + 256*r;
            int k   = idx >> 5;
            int n4  = (idx & 31) << 2;
            float4 v = *(const float4*)(Wcat + (size_t)(kt+k)*PCOLS + nb + n4);
            *(float4*)(&Bs[k][n4]) = v;
        }
        __syncthreads();
        #pragma unroll
        for (int k = 0; k < BK; ++k) {
            float4 a0 = *(const float4*)(&As[k][ty*8]);
            float4 a1 = *(const float4*)(&As[k][ty*8+4]);
            float4 b0 = *(const float4*)(&Bs[k][tx*4]);       // 2-way bank alias: free
            float4 b1 = *(const float4*)(&Bs[k][64+tx*4]);
            fma4(c0[0],a0.x,b0); fma4(c1[0],a0.x,b1);
            fma4(c0[1],a0.y,b0); fma4(c1[1],a0.y,b1);
            fma4(c0[2],a0.z,b0); fma4(c1[2],a0.z,b1);
            fma4(c0[3],a0.w,b0); fma4(c1[3],a0.w,b1);
            fma4(c0[4],a1.x,b0); fma4(c1[4],a1.x,b1);
            fma4(c0[5],a1.y,b0); fma4(c1[5],a1.y,b1);
            fma4(c0[6],a1.z,b0); fma4(c1[6],a1.z,b1);
            fma4(c0[7],a1.w,b0); fma4(c1[7],a1.w,b1);
        }
        __syncthreads();
    }
    float4 bias0 = *(const float4*)(bcat + nb + tx*4);
    float4 bias1 = *(const float4*)(bcat + nb + 64 + tx*4);
    bool y0blk = (nb == 0);
    #pragma unroll
    for (int i = 0; i < 8; ++i) {
        int gm = mb + ty*8 + i;
        if (gm < M) {
            float4 o0, o1;
            o0.x = c0[i].x+bias0.x; o0.y = c0[i].y+bias0.y;
            o0.z = c0[i].z+bias0.z; o0.w = c0[i].w+bias0.w;
            o1.x = c1[i].x+bias1.x; o1.y = c1[i].y+bias1.y;
            o1.z = c1[i].z+bias1.z; o1.w = c1[i].w+bias1.w;
            *(float4*)(P + (size_t)gm*PCOLS + nb + tx*4)      = o0;
            *(float4*)(P + (size_t)gm*PCOLS + nb + 64 + tx*4) = o1;
            if (y0blk) {
                ushort4 u0 = make_ushort4(f2bfu(o0.x), f2bfu(o0.y), f2bfu(o0.z), f2bfu(o0.w));
                *(ushort4*)(Y0b + (size_t)gm*96 + tx*4) = u0;
                if (tx < 8) {   // cols 64..95
                    ushort4 u1 = make_ushort4(f2bfu(o1.x), f2bfu(o1.y), f2bfu(o1.z), f2bfu(o1.w));
                    *(ushort4*)(Y0b + (size_t)gm*96 + 64 + tx*4) = u1;
                }
            }
        }
    }
}

// ---------- fused lap(96 feats, bf16 gather) + grouped conv ----------
// Wave per node; lane L holds feature pair {2L,2L+1} (L<48). 20 nodes/block, 5 trips/wave.
#define CPB 20
#define GRID_AB (N_NODES / CPB)   // 2500

template<int HO>   // 32 (blk) or 64 (post)
__global__ __launch_bounds__(256) void lap_conv(
    const ushortT* __restrict__ Xb,     // [N,96] bf16 gather source
    const float*   __restrict__ Pown,   // fp32 own-x source ([N,512] cols 0..95) or null
    const float*   __restrict__ Z,      // [N,512] + col offset applied
    const int* __restrict__ src, const int* __restrict__ row_ptr,
    const float* __restrict__ Wg,       // [3,32,HO] flat
    const float* __restrict__ bg,       // [3*HO]
    ushortT* __restrict__ outb)         // [N, 3*HO] bf16
{
    __shared__ float wT[3*HO*34];       // transposed+padded: [w][j][34] -> idx w*HO*34 + j*34 + i
    __shared__ float bS[3*HO];
    __shared__ __align__(8) float sm[4][96];
    for (int idx = threadIdx.x; idx < 3*32*HO; idx += 256) {
        int w = idx / (32*HO);
        int r = idx - w*32*HO;
        int i = r / HO;
        int j = r - i*HO;
        wT[(w*HO + j)*34 + i] = Wg[idx];
    }
    for (int idx = threadIdx.x; idx < 3*HO; idx += 256) bS[idx] = bg[idx];
    __syncthreads();

    int wv = threadIdx.x >> 6, lane = threadIdx.x & 63;
    int pL = lane < 48 ? lane : 0;
    bool pv = lane < 48;

    #pragma unroll 1
    for (int trip = 0; trip < CPB/4; ++trip) {
        int t = blockIdx.x * CPB + wv + 4*trip;
        int lo = row_ptr[t], hi = row_ptr[t+1];
        float2 a0={0,0},a1={0,0},a2={0,0},a3={0,0};
        for (int base = lo; base < hi; base += 64) {
            int cnt = hi - base; if (cnt > 64) cnt = 64;
            int sv = src[base + (lane < cnt ? lane : cnt-1)];
            int j = 0;
            for (; j + 4 <= cnt; j += 4) {
                int i0=__shfl(sv,j), i1=__shfl(sv,j+1), i2=__shfl(sv,j+2), i3=__shfl(sv,j+3);
                uintT u0 = *(const uintT*)(Xb + (size_t)i0*96 + 2*pL);
                uintT u1 = *(const uintT*)(Xb + (size_t)i1*96 + 2*pL);
                uintT u2 = *(const uintT*)(Xb + (size_t)i2*96 + 2*pL);
                uintT u3 = *(const uintT*)(Xb + (size_t)i3*96 + 2*pL);
                a0.x += bflo(u0); a0.y += bfhi(u0);
                a1.x += bflo(u1); a1.y += bfhi(u1);
                a2.x += bflo(u2); a2.y += bfhi(u2);
                a3.x += bflo(u3); a3.y += bfhi(u3);
            }
            for (; j < cnt; ++j) {
                int i0 = __shfl(sv,j);
                uintT u0 = *(const uintT*)(Xb + (size_t)i0*96 + 2*pL);
                a0.x += bflo(u0); a0.y += bfhi(u0);
            }
        }
        float sx = (a0.x+a1.x)+(a2.x+a3.x);
        float sy = (a0.y+a1.y)+(a2.y+a3.y);
        int deg = hi - lo;
        float inv = deg > 0 ? 1.f/(float)deg : 0.f;
        float mf  = deg > 0 ? 1.f : 0.f;
        if (pv) {
            float xx, xy;
            if (Pown) {
                float2 xr = *(const float2*)(Pown + (size_t)t*PCOLS + 2*pL);
                xx = xr.x; xy = xr.y;
            } else {
                uintT ux = *(const uintT*)(Xb + (size_t)t*96 + 2*pL);
                xx = bflo(ux); xy = bfhi(ux);
            }
            float2 zr = *(const float2*)(Z + (size_t)t*PCOLS + 2*pL);
            sm[wv][2*pL]   = fmaxf(mf*xx - sx*inv + zr.x, 0.f);
            sm[wv][2*pL+1] = fmaxf(mf*xy - sy*inv + zr.y, 0.f);
        }
        __syncthreads();
        // conv: outputs c = lane (+64k); w = c/HO... c in [0, 3*HO)
        {
            int c = lane;                // HO=32: c<64 covers w=0,1 ; HO=64: w=0
            int w = c / HO, jj = c - w*HO;
            const float* wp = &wT[(w*HO + jj)*34];
            const float* sp = &sm[wv][w*32];
            float s1 = bS[c];
            #pragma unroll
            for (int i = 0; i < 32; i += 2) {
                float2 svv = *(const float2*)(sp + i);
                float2 wvv = *(const float2*)(wp + i);
                s1 = fmaf(svv.x, wvv.x, s1);
                s1 = fmaf(svv.y, wvv.y, s1);
            }
            outb[(size_t)t*(3*HO) + c] = f2bfu(s1);
            #pragma unroll
            for (int extra = 64; extra < 3*HO; extra += 64) {
                int c2 = extra + lane;
                int w2 = c2 / HO, j2 = c2 - w2*HO;
                const float* wp2 = &wT[(w2*HO + j2)*34];
                const float* sp2 = &sm[wv][w2*32];
                float s2 = bS[c2];
                #pragma unroll
                for (int i = 0; i < 32; i += 2) {
                    float2 svv = *(const float2*)(sp2 + i);
                    float2 wvv = *(const float2*)(wp2 + i);
                    s2 = fmaf(svv.x, wvv.x, s2);
                    s2 = fmaf(svv.y, wvv.y, s2);
                }
                outb[(size_t)t*(3*HO) + c2] = f2bfu(s2);
            }
        }
        __syncthreads();
    }
}

// HO=32 special: 96 outputs, lanes 0..31 also do c=64+lane
template<>
__global__ __launch_bounds__(256) void lap_conv<32>(
    const ushortT* __restrict__ Xb, const float* __restrict__ Pown,
    const float* __restrict__ Z,
    const int* __restrict__ src, const int* __restrict__ row_ptr,
    const float* __restrict__ Wg, const float* __restrict__ bg,
    ushortT* __restrict__ outb)
{
    __shared__ float wT[3*32*34];
    __shared__ float bS[96];
    __shared__ __align__(8) float sm[4][96];
    for (int idx = threadIdx.x; idx < 3*32*32; idx += 256) {
        int w = idx >> 10;
        int r = idx & 1023;
        int i = r >> 5;
        int j = r & 31;
        wT[(w*32 + j)*34 + i] = Wg[idx];
    }
    if (threadIdx.x < 96) bS[threadIdx.x] = bg[threadIdx.x];
    __syncthreads();

    int wv = threadIdx.x >> 6, lane = threadIdx.x & 63;
    int pL = lane < 48 ? lane : 0;
    bool pv = lane < 48;

    #pragma unroll 1
    for (int trip = 0; trip < CPB/4; ++trip) {
        int t = blockIdx.x * CPB + wv + 4*trip;
        int lo = row_ptr[t], hi = row_ptr[t+1];
        float2 a0={0,0},a1={0,0},a2={0,0},a3={0,0};
        for (int base = lo; base < hi; base += 64) {
            int cnt = hi - base; if (cnt > 64) cnt = 64;
            int sv = src[base + (lane < cnt ? lane : cnt-1)];
            int j = 0;
            for (; j + 4 <= cnt; j += 4) {
                int i0=__shfl(sv,j), i1=__shfl(sv,j+1), i2=__shfl(sv,j+2), i3=__shfl(sv,j+3);
                uintT u0 = *(const uintT*)(Xb + (size_t)i0*96 + 2*pL);
                uintT u1 = *(const uintT*)(Xb + (size_t)i1*96 + 2*pL);
                uintT u2 = *(const uintT*)(Xb + (size_t)i2*96 + 2*pL);
                uintT u3 = *(const uintT*)(Xb + (size_t)i3*96 + 2*pL);
                a0.x += bflo(u0); a0.y += bfhi(u0);
                a1.x += bflo(u1); a1.y += bfhi(u1);
                a2.x += bflo(u2); a2.y += bfhi(u2);
                a3.x += bflo(u3); a3.y += bfhi(u3);
            }
            for (; j < cnt; ++j) {
                int i0 = __shfl(sv,j);
                uintT u0 = *(const uintT*)(Xb + (size_t)i0*96 + 2*pL);
                a0.x += bflo(u0); a0.y += bfhi(u0);
            }
        }
        float sx = (a0.x+a1.x)+(a2.x+a3.x);
        float sy = (a0.y+a1.y)+(a2.y+a3.y);
        int deg = hi - lo;
        float inv = deg > 0 ? 1.f/(float)deg : 0.f;
        float mf  = deg > 0 ? 1.f : 0.f;
        if (pv) {
            float xx, xy;
            if (Pown) {
                float2 xr = *(const float2*)(Pown + (size_t)t*PCOLS + 2*pL);
                xx = xr.x; xy = xr.y;
            } else {
                uintT ux = *(const uintT*)(Xb + (size_t)t*96 + 2*pL);
                xx = bflo(ux); xy = bfhi(ux);
            }
            float2 zr = *(const float2*)(Z + (size_t)t*PCOLS + 2*pL);
            sm[wv][2*pL]   = fmaxf(mf*xx - sx*inv + zr.x, 0.f);
            sm[wv][2*pL+1] = fmaxf(mf*xy - sy*inv + zr.y, 0.f);
        }
        __syncthreads();
        {
            int c = lane;               // w = lane>>5 in {0,1}
            int w = c >> 5, jj = c & 31;
            const float* wp = &wT[(w*32 + jj)*34];
            const float* sp = &sm[wv][w*32];
            float s1 = bS[c];
            #pragma unroll
            for (int i = 0; i < 32; i += 2) {
                float2 svv = *(const float2*)(sp + i);
                float2 wvv = *(const float2*)(wp + i);
                s1 = fmaf(svv.x, wvv.x, s1);
                s1 = fmaf(svv.y, wvv.y, s1);
            }
            outb[(size_t)t*96 + c] = f2bfu(s1);
            if (lane < 32) {
                int c2 = 64 + lane;     // w=2, j=lane
                const float* wp2 = &wT[(2*32 + lane)*34];
                const float* sp2 = &sm[wv][64];
                float s2 = bS[c2];
                #pragma unroll
                for (int i = 0; i < 32; i += 2) {
                    float2 svv = *(const float2*)(sp2 + i);
                    float2 wvv = *(const float2*)(wp2 + i);
                    s2 = fmaf(svv.x, wvv.x, s2);
                    s2 = fmaf(svv.y, wvv.y, s2);
                }
                outb[(size_t)t*96 + c2] = f2bfu(s2);
            }
        }
        __syncthreads();
    }
}

// ---------- final: relu(Lap(h2b)+Zpost), width-mean via shfl -> out[N,64] ----------
__global__ void lap_final(const ushortT* __restrict__ Xb,  // [N,192] bf16
                          const float* __restrict__ Z,     // P + 288
                          const int* __restrict__ src, const int* __restrict__ row_ptr,
                          float* __restrict__ out, int N)
{
    int wid  = (int)(((size_t)blockIdx.x * blockDim.x + threadIdx.x) >> 6);
    int lane = threadIdx.x & 63;
    if (wid >= N) return;
    int lo = row_ptr[wid], hi = row_ptr[wid+1];
    int pL2 = lane & 31;
    float2 a0={0,0},a1={0,0},a2={0,0},a3={0,0};   // feats 2L,2L+1
    float2 b0={0,0},b1={0,0},b2={0,0},b3={0,0};   // feats 128+2L' (lanes<32)
    for (int base = lo; base < hi; base += 64) {
        int cnt = hi - base; if (cnt > 64) cnt = 64;
        int sv = src[base + (lane < cnt ? lane : cnt-1)];
        int j = 0;
        for (; j + 4 <= cnt; j += 4) {
            int i0=__shfl(sv,j), i1=__shfl(sv,j+1), i2=__shfl(sv,j+2), i3=__shfl(sv,j+3);
            uintT ua0 = *(const uintT*)(Xb + (size_t)i0*192 + 2*lane);
            uintT ua1 = *(const uintT*)(Xb + (size_t)i1*192 + 2*lane);
            uintT ua2 = *(const uintT*)(Xb + (size_t)i2*192 + 2*lane);
            uintT ua3 = *(const uintT*)(Xb + (size_t)i3*192 + 2*lane);
            uintT ub0 = *(const uintT*)(Xb + (size_t)i0*192 + 128 + 2*pL2);
            uintT ub1 = *(const uintT*)(Xb + (size_t)i1*192 + 128 + 2*pL2);
            uintT ub2 = *(const uintT*)(Xb + (size_t)i2*192 + 128 + 2*pL2);
            uintT ub3 = *(const uintT*)(Xb + (size_t)i3*192 + 128 + 2*pL2);
            a0.x += bflo(ua0); a0.y += bfhi(ua0);
            a1.x += bflo(ua1); a1.y += bfhi(ua1);
            a2.x += bflo(ua2); a2.y += bfhi(ua2);
            a3.x += bflo(ua3); a3.y += bfhi(ua3);
            b0.x += bflo(ub0); b0.y += bfhi(ub0);
            b1.x += bflo(ub1); b1.y += bfhi(ub1);
            b2.x += bflo(ub2); b2.y += bfhi(ub2);
            b3.x += bflo(ub3); b3.y += bfhi(ub3);
        }
        for (; j < cnt; ++j) {
            int i0 = __shfl(sv,j);
            uintT ua0 = *(const uintT*)(Xb + (size_t)i0*192 + 2*lane);
            uintT ub0 = *(const uintT*)(Xb + (size_t)i0*192 + 128 + 2*pL2);
            a0.x += bflo(ua0); a0.y += bfhi(ua0);
            b0.x += bflo(ub0); b0.y += bfhi(ub0);
        }
    }
    float sax = (a0.x+a1.x)+(a2.x+a3.x);
    float say = (a0.y+a1.y)+(a2.y+a3.y);
    float sbx = (b0.x+b1.x)+(b2.x+b3.x);
    float sby = (b0.y+b1.y)+(b2.y+b3.y);
    int deg = hi - lo;
    float inv = deg > 0 ? 1.f/(float)deg : 0.f;
    float mf  = deg > 0 ? 1.f : 0.f;
    uintT uxa = *(const uintT*)(Xb + (size_t)wid*192 + 2*lane);
    uintT uxb = *(const uintT*)(Xb + (size_t)wid*192 + 128 + 2*pL2);
    float2 za  = *(const float2*)(Z + (size_t)wid*PCOLS + 2*lane);
    float2 zb  = *(const float2*)(Z + (size_t)wid*PCOLS + 128 + 2*pL2);
    float2 oa, ob;
    oa.x = fmaxf(mf*bflo(uxa) - sax*inv + za.x, 0.f);
    oa.y = fmaxf(mf*bfhi(uxa) - say*inv + za.y, 0.f);
    ob.x = fmaxf(mf*bflo(uxb) - sbx*inv + zb.x, 0.f);
    ob.y = fmaxf(mf*bfhi(uxb) - sby*inv + zb.y, 0.f);
    // out[f] = (o[3f] + o[3f+1] + o[3f+2]) / 3, f = lane
    float r = 0.f;
    #pragma unroll
    for (int q = 0; q < 3; ++q) {
        int g  = 3*lane + q;
        int pa = (g >> 1) & 63;
        int pb = ((g - 128) >> 1) & 63;
        float cax = __shfl(oa.x, pa), cay = __shfl(oa.y, pa);
        float cbx = __shfl(ob.x, pb), cby = __shfl(ob.y, pb);
        float v = (g < 128) ? ((g & 1) ? cay : cax)
                            : ((g & 1) ? cby : cbx);
        r += v;
    }
    out[(size_t)wid*64 + lane] = r * (1.0f/3.0f);
}

extern "C" void kernel_launch(void* const* d_in, const int* in_sizes, int n_in,
                              void* d_out, int out_size, void* d_ws, size_t ws_size,
                              hipStream_t stream)
{
    const float* data    = (const float*)d_in[0];
    const int*   src     = (const int*)  d_in[1];
    const int*   tgt     = (const int*)  d_in[2];
    const float* W_pre   = (const float*)d_in[3];
    const float* b_pre   = (const float*)d_in[4];
    const float* T_pre   = (const float*)d_in[5];
    const float* bT_pre  = (const float*)d_in[6];
    const float* W_blk   = (const float*)d_in[7];
    const float* b_blk   = (const float*)d_in[8];
    const float* T_blk   = (const float*)d_in[9];
    const float* bT_blk  = (const float*)d_in[10];
    const float* W_post  = (const float*)d_in[11];
    const float* b_post  = (const float*)d_in[12];
    const float* T_post  = (const float*)d_in[13];
    const float* bT_post = (const float*)d_in[14];
    float* out = (float*)d_out;

    float* ws   = (float*)d_ws;
    float*   P    = ws;                                    // N*512 f32
    float*   Wcat = P + (size_t)N_NODES * PCOLS;           // 128*512
    float*   bcat = Wcat + 128*512;                        // 512
    int*     row_ptr = (int*)(bcat + 512);                 // N+1 (+pad)
    ushortT* Y0b  = (ushortT*)(row_ptr + N_NODES + 8);     // N*96 bf16
    ushortT* h1b  = Y0b + (size_t)N_NODES * 96;            // N*96 bf16
    ushortT* h2b  = h1b + (size_t)N_NODES * 96;            // N*192 bf16

    pack_weights<<<(IN_F*PCOLS + 255)/256, 256, 0, stream>>>(
        W_pre, b_pre, T_pre, bT_pre, T_blk, bT_blk, T_post, bT_post, Wcat, bcat);

    build_row_ptr<<<(N_NODES + 1 + 255)/256, 256, 0, stream>>>(tgt, row_ptr, E_EDGES, N_NODES + 1);

    dim3 gg(PCOLS/BN, (N_NODES + BM - 1)/BM);   // x = col tile (4), y = row tile (391)
    gemm_fused<<<gg, 256, 0, stream>>>(data, Wcat, bcat, P, Y0b, N_NODES);

    // layer 1 + conv_blk -> h1b
    lap_conv<32><<<GRID_AB, 256, 0, stream>>>(Y0b, P, P + 96, src, row_ptr, W_blk, b_blk, h1b);
    // layer 2 + conv_post -> h2b
    lap_conv<64><<<GRID_AB, 256, 0, stream>>>(h1b, nullptr, P + 192, src, row_ptr, W_post, b_post, h2b);
    // layer 3 + width-mean
    lap_final<<<(N_NODES*64)/256, 256, 0, stream>>>(h2b, P + 288, src, row_ptr, out, N_NODES);
}

// Round 4
// 337.736 us; speedup vs baseline: 2.0978x; 1.1345x over previous
//
#include <hip/hip_runtime.h>
#include <cstdint>
#include <cstddef>

#define N_NODES 50000
#define E_EDGES 800000
#define IN_F    128
#define PCOLS   512   // P: [0,96) Y0 | [96,192) Zpre | [192,288) Zblk | [288,480) Zpost | pad

typedef unsigned short ushortT;
typedef unsigned int   uintT;
typedef __attribute__((ext_vector_type(8))) short s8v;   // 8 bf16 (4 VGPR)
typedef __attribute__((ext_vector_type(4))) float f4v;   // 4 fp32 acc

__device__ __forceinline__ float bflo(uintT u){ union{uintT i;float f;}c; c.i=u<<16; return c.f; }
__device__ __forceinline__ float bfhi(uintT u){ union{uintT i;float f;}c; c.i=u&0xFFFF0000u; return c.f; }
__device__ __forceinline__ ushortT f2bfu(float f){
    union{float f;uintT u;}c; c.f=f;
    uintT r = c.u + 0x7FFF + ((c.u>>16)&1);
    return (ushortT)(r>>16);
}
__device__ __forceinline__ uintT pack2(float a, float b){
    return (uintT)f2bfu(a) | ((uintT)f2bfu(b) << 16);
}

// ---------- pack weights into Wb [512][128] bf16 (transposed) + bcat[512] fp32 ----------
__global__ void pack_weights(const float* __restrict__ Wp,  const float* __restrict__ bp,
                             const float* __restrict__ Tp,  const float* __restrict__ bTp,
                             const float* __restrict__ Tb,  const float* __restrict__ bTb,
                             const float* __restrict__ Tpo, const float* __restrict__ bTpo,
                             ushortT* __restrict__ Wb, float* __restrict__ bcat)
{
    int id = blockIdx.x * 256 + threadIdx.x;
    if (id >= IN_F * PCOLS) return;
    int k = id >> 9;
    int c = id & 511;
    float v;
    if      (c < 96)  v = Wp [k*96  + c];
    else if (c < 192) v = Tp [k*96  + (c-96)];
    else if (c < 288) v = Tb [k*96  + (c-192)];
    else if (c < 480) v = Tpo[k*192 + (c-288)];
    else              v = 0.f;
    Wb[(size_t)c*IN_F + k] = f2bfu(v);
    if (k == 0) {
        float b;
        if      (c < 96)  b = bp  [c];
        else if (c < 192) b = bTp [c-96];
        else if (c < 288) b = bTb [c-192];
        else if (c < 480) b = bTpo[c-288];
        else              b = 0.f;
        bcat[c] = b;
    }
}

// ---------- convert data fp32 -> Ab bf16 [N][128] ----------
__global__ void convert_data(const float* __restrict__ A, ushortT* __restrict__ Ab)
{
    int gid = blockIdx.x * 256 + threadIdx.x;      // 800000 threads, 8 elems each
    size_t off = (size_t)gid * 8;
    float4 v0 = *(const float4*)(A + off);
    float4 v1 = *(const float4*)(A + off + 4);
    uint4 u;
    u.x = pack2(v0.x, v0.y); u.y = pack2(v0.z, v0.w);
    u.z = pack2(v1.x, v1.y); u.w = pack2(v1.z, v1.w);
    *(uint4*)(Ab + off) = u;
}

// ---------- row_ptr via binary search on sorted tgt ----------
__global__ void build_row_ptr(const int* __restrict__ tgt, int* __restrict__ row_ptr,
                              int E, int Np1)
{
    int t = blockIdx.x * 256 + threadIdx.x;
    if (t >= Np1) return;
    int lo = 0, hi = E;
    while (lo < hi) {
        int mid = (lo + hi) >> 1;
        if (tgt[mid] < t) lo = mid + 1; else hi = mid;
    }
    row_ptr[t] = lo;
}

// ---------- MFMA GEMM: P[M,512] = Ab[M,128] @ Wb^T + bcat ; also emit Y0b bf16 ----------
// 128x128 block tile, 4 waves in 2x2, each wave 64x64 via 4x4 MFMA 16x16x32.
// LDS: BK=64 slab, rows padded to 72 ushorts (144 B -> (row*9+q)%8 uniform bank-quads).
__global__ __launch_bounds__(256, 2) void gemm_mfma(const ushortT* __restrict__ Ab,
                                                    const ushortT* __restrict__ Wb,
                                                    const float* __restrict__ bcat,
                                                    float* __restrict__ P,
                                                    ushortT* __restrict__ Y0b, int M)
{
    __shared__ ushortT Asl[128][72];
    __shared__ ushortT Bsl[128][72];
    int tid = threadIdx.x;
    int nb = blockIdx.x * 128;       // col tile (x fastest: 4 col tiles share A via L2)
    int mb = blockIdx.y * 128;
    int wv = tid >> 6, lane = tid & 63;
    int wm = wv >> 1, wn = wv & 1;
    int cl = lane & 15, q = lane >> 4;

    f4v acc[4][4];
    #pragma unroll
    for (int i = 0; i < 4; ++i)
        #pragma unroll
        for (int j = 0; j < 4; ++j) acc[i][j] = (f4v)0.f;

    for (int kt = 0; kt < IN_F; kt += 64) {
        if (kt) __syncthreads();
        // stage A: 128 rows x 64 bf16 = 1024 16B-chunks
        #pragma unroll
        for (int r = 0; r < 4; ++r) {
            int idx = tid + 256*r;
            int row = idx >> 3, qq = idx & 7;
            int gm = mb + row;
            uint4 v = make_uint4(0,0,0,0);
            if (gm < M) v = *(const uint4*)(Ab + (size_t)gm*IN_F + kt + qq*8);
            *(uint4*)(&Asl[row][qq*8]) = v;
        }
        // stage B: 128 n-rows x 64 bf16
        #pragma unroll
        for (int r = 0; r < 4; ++r) {
            int idx = tid + 256*r;
            int row = idx >> 3, qq = idx & 7;
            uint4 v = *(const uint4*)(Wb + (size_t)(nb+row)*IN_F + kt + qq*8);
            *(uint4*)(&Bsl[row][qq*8]) = v;
        }
        __syncthreads();
        #pragma unroll
        for (int ks = 0; ks < 2; ++ks) {
            int ko = ks*32 + q*8;
            s8v af[4], bf[4];
            #pragma unroll
            for (int mt = 0; mt < 4; ++mt)
                af[mt] = *(const s8v*)(&Asl[wm*64 + mt*16 + cl][ko]);
            #pragma unroll
            for (int nt = 0; nt < 4; ++nt)
                bf[nt] = *(const s8v*)(&Bsl[wn*64 + nt*16 + cl][ko]);
            #pragma unroll
            for (int mt = 0; mt < 4; ++mt)
                #pragma unroll
                for (int nt = 0; nt < 4; ++nt)
                    acc[mt][nt] = __builtin_amdgcn_mfma_f32_16x16x32_bf16(af[mt], bf[nt], acc[mt][nt], 0, 0, 0);
        }
    }

    // epilogue: C layout col=lane&15, row=q*4+reg
    bool y0blk = (nb == 0) && (wn == 0);
    #pragma unroll
    for (int nt = 0; nt < 4; ++nt) {
        int gn = nb + wn*64 + nt*16 + cl;
        float bv = bcat[gn];
        bool doY = y0blk && (nt < 6) && (gn < 96);
        #pragma unroll
        for (int mt = 0; mt < 4; ++mt) {
            int gm0 = mb + wm*64 + mt*16 + q*4;
            #pragma unroll
            for (int r = 0; r < 4; ++r) {
                int gm = gm0 + r;
                if (gm < M) {
                    float val = acc[mt][nt][r] + bv;
                    P[(size_t)gm*PCOLS + gn] = val;
                    if (doY) Y0b[(size_t)gm*96 + gn] = f2bfu(val);
                }
            }
        }
    }
}

// ---------- fused lap(96 feats, bf16 gather, 16-deep MLP) + grouped conv ----------
#define CPB 20
#define GRID_AB (N_NODES / CPB)   // 2500

template<int HO>   // 32 (blk) or 64 (post)
__global__ __launch_bounds__(256) void lap_conv(
    const ushortT* __restrict__ Xb,     // [N,96] bf16 gather source
    const float*   __restrict__ Pown,   // fp32 own-x ([N,512] cols 0..95) or null
    const float*   __restrict__ Z,      // [N,512] + col offset applied
    const int* __restrict__ src, const int* __restrict__ row_ptr,
    const float* __restrict__ Wg,       // [3,32,HO] flat
    const float* __restrict__ bg,       // [3*HO]
    ushortT* __restrict__ outb)         // [N, 3*HO] bf16
{
    __shared__ float wT[3*HO*34];       // [w][j][34] transposed+padded
    __shared__ float bS[3*HO];
    __shared__ __align__(8) float sm[4][96];
    for (int idx = threadIdx.x; idx < 3*32*HO; idx += 256) {
        int w = idx / (32*HO);
        int r = idx - w*32*HO;
        int i = r / HO;
        int j = r - i*HO;
        wT[(w*HO + j)*34 + i] = Wg[idx];
    }
    for (int idx = threadIdx.x; idx < 3*HO; idx += 256) bS[idx] = bg[idx];
    __syncthreads();

    int wv = threadIdx.x >> 6, lane = threadIdx.x & 63;
    int pL = lane < 48 ? lane : 0;
    bool pv = lane < 48;

    #pragma unroll 1
    for (int trip = 0; trip < CPB/4; ++trip) {
        int t = blockIdx.x * CPB + wv + 4*trip;
        int lo = row_ptr[t], hi = row_ptr[t+1];
        // hoist own-x and Z loads (independent of gather)
        float xx, xy;
        if (Pown) {
            float2 xr = *(const float2*)(Pown + (size_t)t*PCOLS + 2*pL);
            xx = xr.x; xy = xr.y;
        } else {
            uintT ux = *(const uintT*)(Xb + (size_t)t*96 + 2*pL);
            xx = bflo(ux); xy = bfhi(ux);
        }
        float2 zr = *(const float2*)(Z + (size_t)t*PCOLS + 2*pL);

        float s0x=0.f,s0y=0.f,s1x=0.f,s1y=0.f,s2x=0.f,s2y=0.f,s3x=0.f,s3y=0.f;
        for (int base = lo; base < hi; base += 64) {
            int cnt = hi - base; if (cnt > 64) cnt = 64;
            int sv = src[base + (lane < cnt ? lane : cnt-1)];
            for (int j0 = 0; j0 < cnt; j0 += 16) {
                uintT u[16];
                #pragma unroll
                for (int k = 0; k < 16; ++k) {
                    int jj = j0 + k;
                    int cj = jj < cnt ? jj : cnt-1;
                    int idx = __shfl(sv, cj);
                    u[k] = *(const uintT*)(Xb + (size_t)idx*96 + 2*pL);
                }
                #pragma unroll
                for (int k = 0; k < 16; ++k) {
                    float mk = (j0 + k) < cnt ? 1.f : 0.f;
                    float lo_ = bflo(u[k]), hi_ = bfhi(u[k]);
                    switch (k & 3) {
                        case 0: s0x = fmaf(mk, lo_, s0x); s0y = fmaf(mk, hi_, s0y); break;
                        case 1: s1x = fmaf(mk, lo_, s1x); s1y = fmaf(mk, hi_, s1y); break;
                        case 2: s2x = fmaf(mk, lo_, s2x); s2y = fmaf(mk, hi_, s2y); break;
                        default:s3x = fmaf(mk, lo_, s3x); s3y = fmaf(mk, hi_, s3y); break;
                    }
                }
            }
        }
        float sx = (s0x+s1x)+(s2x+s3x);
        float sy = (s0y+s1y)+(s2y+s3y);
        int deg = hi - lo;
        float inv = deg > 0 ? 1.f/(float)deg : 0.f;
        float mf  = deg > 0 ? 1.f : 0.f;
        if (pv) {
            sm[wv][2*pL]   = fmaxf(mf*xx - sx*inv + zr.x, 0.f);
            sm[wv][2*pL+1] = fmaxf(mf*xy - sy*inv + zr.y, 0.f);
        }
        __syncthreads();
        {
            int c = lane;
            int w = c / HO, jj = c - w*HO;
            const float* wp = &wT[(w*HO + jj)*34];
            const float* sp = &sm[wv][w*32];
            float s1 = bS[c];
            #pragma unroll
            for (int i = 0; i < 32; i += 2) {
                float2 svv = *(const float2*)(sp + i);
                float2 wvv = *(const float2*)(wp + i);
                s1 = fmaf(svv.x, wvv.x, s1);
                s1 = fmaf(svv.y, wvv.y, s1);
            }
            outb[(size_t)t*(3*HO) + c] = f2bfu(s1);
            #pragma unroll
            for (int extra = 64; extra < 3*HO; extra += 64) {
                int c2 = extra + lane;
                if (c2 < 3*HO) {
                    int w2 = c2 / HO, j2 = c2 - w2*HO;
                    const float* wp2 = &wT[(w2*HO + j2)*34];
                    const float* sp2 = &sm[wv][w2*32];
                    float s2 = bS[c2];
                    #pragma unroll
                    for (int i = 0; i < 32; i += 2) {
                        float2 svv = *(const float2*)(sp2 + i);
                        float2 wvv = *(const float2*)(wp2 + i);
                        s2 = fmaf(svv.x, wvv.x, s2);
                        s2 = fmaf(svv.y, wvv.y, s2);
                    }
                    outb[(size_t)t*(3*HO) + c2] = f2bfu(s2);
                }
            }
        }
        __syncthreads();
    }
}

// ---------- final: relu(Lap(h2b)+Zpost), width-mean via shfl -> out[N,64] ----------
__global__ void lap_final(const ushortT* __restrict__ Xb,  // [N,192] bf16
                          const float* __restrict__ Z,     // P + 288
                          const int* __restrict__ src, const int* __restrict__ row_ptr,
                          float* __restrict__ out, int N)
{
    int wid  = (int)(((size_t)blockIdx.x * blockDim.x + threadIdx.x) >> 6);
    int lane = threadIdx.x & 63;
    if (wid >= N) return;
    int lo = row_ptr[wid], hi = row_ptr[wid+1];
    int pL2 = lane & 31;
    // hoist own-x and Z
    uintT uxa = *(const uintT*)(Xb + (size_t)wid*192 + 2*lane);
    uintT uxb = *(const uintT*)(Xb + (size_t)wid*192 + 128 + 2*pL2);
    float2 za  = *(const float2*)(Z + (size_t)wid*PCOLS + 2*lane);
    float2 zb  = *(const float2*)(Z + (size_t)wid*PCOLS + 128 + 2*pL2);

    float a0x=0,a0y=0,a1x=0,a1y=0;     // feats 2L,2L+1 (two chains)
    float b0x=0,b0y=0,b1x=0,b1y=0;     // feats 128+2L'
    for (int base = lo; base < hi; base += 64) {
        int cnt = hi - base; if (cnt > 64) cnt = 64;
        int sv = src[base + (lane < cnt ? lane : cnt-1)];
        for (int j0 = 0; j0 < cnt; j0 += 8) {
            uintT ua[8], ub[8];
            #pragma unroll
            for (int k = 0; k < 8; ++k) {
                int jj = j0 + k;
                int cj = jj < cnt ? jj : cnt-1;
                int idx = __shfl(sv, cj);
                const ushortT* rp = Xb + (size_t)idx*192;
                ua[k] = *(const uintT*)(rp + 2*lane);
                ub[k] = *(const uintT*)(rp + 128 + 2*pL2);
            }
            #pragma unroll
            for (int k = 0; k < 8; ++k) {
                float mk = (j0 + k) < cnt ? 1.f : 0.f;
                if (k & 1) {
                    a1x = fmaf(mk, bflo(ua[k]), a1x); a1y = fmaf(mk, bfhi(ua[k]), a1y);
                    b1x = fmaf(mk, bflo(ub[k]), b1x); b1y = fmaf(mk, bfhi(ub[k]), b1y);
                } else {
                    a0x = fmaf(mk, bflo(ua[k]), a0x); a0y = fmaf(mk, bfhi(ua[k]), a0y);
                    b0x = fmaf(mk, bflo(ub[k]), b0x); b0y = fmaf(mk, bfhi(ub[k]), b0y);
                }
            }
        }
    }
    float sax = a0x + a1x, say = a0y + a1y;
    float sbx = b0x + b1x, sby = b0y + b1y;
    int deg = hi - lo;
    float inv = deg > 0 ? 1.f/(float)deg : 0.f;
    float mf  = deg > 0 ? 1.f : 0.f;
    float2 oa, ob;
    oa.x = fmaxf(mf*bflo(uxa) - sax*inv + za.x, 0.f);
    oa.y = fmaxf(mf*bfhi(uxa) - say*inv + za.y, 0.f);
    ob.x = fmaxf(mf*bflo(uxb) - sbx*inv + zb.x, 0.f);
    ob.y = fmaxf(mf*bfhi(uxb) - sby*inv + zb.y, 0.f);
    float r = 0.f;
    #pragma unroll
    for (int qq = 0; qq < 3; ++qq) {
        int g  = 3*lane + qq;
        int pa = (g >> 1) & 63;
        int pb = ((g - 128) >> 1) & 63;
        float cax = __shfl(oa.x, pa), cay = __shfl(oa.y, pa);
        float cbx = __shfl(ob.x, pb), cby = __shfl(ob.y, pb);
        float v = (g < 128) ? ((g & 1) ? cay : cax)
                            : ((g & 1) ? cby : cbx);
        r += v;
    }
    out[(size_t)wid*64 + lane] = r * (1.0f/3.0f);
}

extern "C" void kernel_launch(void* const* d_in, const int* in_sizes, int n_in,
                              void* d_out, int out_size, void* d_ws, size_t ws_size,
                              hipStream_t stream)
{
    const float* data    = (const float*)d_in[0];
    const int*   src     = (const int*)  d_in[1];
    const int*   tgt     = (const int*)  d_in[2];
    const float* W_pre   = (const float*)d_in[3];
    const float* b_pre   = (const float*)d_in[4];
    const float* T_pre   = (const float*)d_in[5];
    const float* bT_pre  = (const float*)d_in[6];
    const float* W_blk   = (const float*)d_in[7];
    const float* b_blk   = (const float*)d_in[8];
    const float* T_blk   = (const float*)d_in[9];
    const float* bT_blk  = (const float*)d_in[10];
    const float* W_post  = (const float*)d_in[11];
    const float* b_post  = (const float*)d_in[12];
    const float* T_post  = (const float*)d_in[13];
    const float* bT_post = (const float*)d_in[14];
    float* out = (float*)d_out;

    float* ws = (float*)d_ws;
    float*   P       = ws;                                  // N*512 f32
    float*   bcat    = P + (size_t)N_NODES * PCOLS;         // 512
    int*     row_ptr = (int*)(bcat + 512);                  // 50008 ints (padded)
    ushortT* Y0b     = (ushortT*)(row_ptr + 50008);         // N*96 bf16
    ushortT* h1b     = Y0b + (size_t)N_NODES * 96;          // N*96 bf16
    ushortT* h2b     = h1b + (size_t)N_NODES * 96;          // N*192 bf16
    ushortT* Ab      = h2b + (size_t)N_NODES * 192;         // N*128 bf16
    ushortT* Wb      = Ab  + (size_t)N_NODES * IN_F;        // 512*128 bf16

    pack_weights<<<(IN_F*PCOLS + 255)/256, 256, 0, stream>>>(
        W_pre, b_pre, T_pre, bT_pre, T_blk, bT_blk, T_post, bT_post, Wb, bcat);

    convert_data<<<(N_NODES*IN_F/8 + 255)/256, 256, 0, stream>>>(data, Ab);

    build_row_ptr<<<(N_NODES + 1 + 255)/256, 256, 0, stream>>>(tgt, row_ptr, E_EDGES, N_NODES + 1);

    dim3 gg(PCOLS/128, (N_NODES + 127)/128);   // (4, 391), col tiles fastest
    gemm_mfma<<<gg, 256, 0, stream>>>(Ab, Wb, bcat, P, Y0b, N_NODES);

    // layer 1 + conv_blk -> h1b
    lap_conv<32><<<GRID_AB, 256, 0, stream>>>(Y0b, P, P + 96, src, row_ptr, W_blk, b_blk, h1b);
    // layer 2 + conv_post -> h2b
    lap_conv<64><<<GRID_AB, 256, 0, stream>>>(h1b, nullptr, P + 192, src, row_ptr, W_post, b_post, h2b);
    // layer 3 + width-mean
    lap_final<<<(N_NODES*64)/256, 256, 0, stream>>>(h2b, P + 288, src, row_ptr, out, N_NODES);
}